// Round 1
// 826.007 us; speedup vs baseline: 1.0428x; 1.0428x over previous
//
#include <hip/hip_runtime.h>
#include <math.h>

typedef unsigned short u16;
typedef __bf16 bf16x8 __attribute__((ext_vector_type(8)));
typedef float f32x4 __attribute__((ext_vector_type(4)));

#define T_TOK 4096
#define DIMD 2048
#define HIDD 1024
#define NEXP 16
#define RMAX 10240
#define MAXBLK 96
#define BM 128
#define BN 128
#define BK 32

__device__ __forceinline__ u16 f2b(float f) {
  unsigned u = __builtin_bit_cast(unsigned, f);
  unsigned r = (u + 0x7FFFu + ((u >> 16) & 1u)) >> 16;  // RNE
  return (u16)r;
}

__device__ __forceinline__ void gld16(const void* g, void* l) {
  __builtin_amdgcn_global_load_lds(
      (const __attribute__((address_space(1))) void*)g,
      (__attribute__((address_space(3))) void*)l, 16, 0, 0);
}

// ---------------- small kernels ----------------

__global__ void k_zero(float* __restrict__ o) {
  const int i = blockIdx.x * blockDim.x + threadIdx.x;
  float4 z = {0.f, 0.f, 0.f, 0.f};
  ((float4*)o)[i] = z;
}

__global__ void k_init(int* perm, int* cnt, int* fill) {
  int i = blockIdx.x * blockDim.x + threadIdx.x;
  if (i < RMAX) perm[i] = -1;
  if (i < NEXP) { cnt[i] = 0; fill[i] = 0; }
}

__global__ void k_cvt(const float* __restrict__ x, u16* __restrict__ xb) {
  const int i = blockIdx.x * blockDim.x + threadIdx.x;
  const float4 v = ((const float4*)x)[i];
  union { u16 u[4]; unsigned long long q; } t;
  t.u[0] = f2b(v.x); t.u[1] = f2b(v.y); t.u[2] = f2b(v.z); t.u[3] = f2b(v.w);
  ((unsigned long long*)xb)[i] = t.q;
}

// transpose+convert: W fp32 [E][K][N] -> Wt bf16 rows of n: Wt[e-part][n][k]
__global__ __launch_bounds__(256)
void k_tr(const float* __restrict__ W, u16* __restrict__ Wt,
          int K, int N, long estride, int ld_out) {
  __shared__ float t[64][65];
  const int e = blockIdx.z;
  const float* Win = W + (size_t)e * (size_t)K * (size_t)N;
  u16* Wo = Wt + (size_t)e * (size_t)estride;
  const int n0 = blockIdx.x * 64, k0 = blockIdx.y * 64;
  const int r = threadIdx.x >> 4;
  const int c = (threadIdx.x & 15) * 4;
#pragma unroll
  for (int p = 0; p < 4; ++p) {
    const int kk = p * 16 + r;
    const float4 v = *(const float4*)&Win[(size_t)(k0 + kk) * N + n0 + c];
    t[kk][c] = v.x; t[kk][c + 1] = v.y; t[kk][c + 2] = v.z; t[kk][c + 3] = v.w;
  }
  __syncthreads();
#pragma unroll
  for (int p = 0; p < 4; ++p) {
    const int nn = p * 16 + r;
    ushort4 o;
    o.x = f2b(t[c + 0][nn]); o.y = f2b(t[c + 1][nn]);
    o.z = f2b(t[c + 2][nn]); o.w = f2b(t[c + 3][nn]);
    *(ushort4*)&Wo[(size_t)(n0 + nn) * ld_out + k0 + c] = o;
  }
}

// gating: fp32 logits = x @ gate_w, softmax, top-2, partial prob sums
__global__ __launch_bounds__(256)
void k_gate(const float* __restrict__ x, const float* __restrict__ gw,
            int* __restrict__ top2i, float* __restrict__ top2w,
            int* __restrict__ cnt, float* __restrict__ partial) {
  const int e = threadIdx.x & 15;
  const int tt = threadIdx.x >> 4;
  const int t = blockIdx.x * 16 + tt;
  const float* xp = x + (size_t)t * DIMD;
  float acc = 0.f;
#pragma unroll 8
  for (int k = 0; k < DIMD; ++k) acc = fmaf(xp[k], gw[k * NEXP + e], acc);
  __shared__ float lg[16][17];
  __shared__ float pr[16][17];
  lg[tt][e] = acc;
  __syncthreads();
  if (e == 0) {
    float l[16];
    float mx = -1e30f;
    for (int j = 0; j < 16; ++j) { l[j] = lg[tt][j]; mx = fmaxf(mx, l[j]); }
    float s = 0.f;
    for (int j = 0; j < 16; ++j) { l[j] = expf(l[j] - mx); s += l[j]; }
    const float inv = 1.f / s;
    float p1 = -1.f, p2 = -1.f; int i1 = 0, i2 = 0;
    for (int j = 0; j < 16; ++j) {
      const float p = l[j] * inv;
      pr[tt][j] = p;
      if (p > p1) { p2 = p1; i2 = i1; p1 = p; i1 = j; }
      else if (p > p2) { p2 = p; i2 = j; }
    }
    const float wsum = p1 + p2;
    top2i[t * 2 + 0] = i1;
    top2i[t * 2 + 1] = i2;
    top2w[t * 2 + 0] = p1 / wsum;
    top2w[t * 2 + 1] = p2 / wsum;
    atomicAdd(&cnt[i1], 1);
    atomicAdd(&cnt[i2], 1);
  }
  __syncthreads();
  if (tt == 0) {
    float s = 0.f;
    for (int j = 0; j < 16; ++j) s += pr[j][e];
    partial[blockIdx.x * 16 + e] = s;
  }
}

__global__ __launch_bounds__(256)
void k_aux(const float* __restrict__ partial, float* __restrict__ auxOut) {
  __shared__ float s[16][17];
  const int e = threadIdx.x & 15, c = threadIdx.x >> 4;
  float a = 0.f;
  for (int b = c; b < 256; b += 16) a += partial[b * 16 + e];
  s[c][e] = a;
  __syncthreads();
  if (threadIdx.x == 0) {
    float aux = 0.f;
    for (int j = 0; j < 16; ++j) {
      float tot = 0.f;
      for (int cc = 0; cc < 16; ++cc) tot += s[cc][j];
      const float m = tot / (float)T_TOK;
      aux += m * m;
    }
    auxOut[0] = aux * (float)NEXP;
  }
}

__global__ void k_off(const int* __restrict__ cnt, int* __restrict__ offs,
                      int* __restrict__ tbl_e, int* __restrict__ tbl_r0,
                      int* __restrict__ nblk) {
  if (threadIdx.x != 0 || blockIdx.x != 0) return;
  int o = 0, nb = 0;
  for (int e = 0; e < NEXP; ++e) {
    offs[e] = o;
    const int b = (cnt[e] + BM - 1) / BM;
    for (int i = 0; i < b; ++i) { tbl_e[nb] = e; tbl_r0[nb] = o + i * BM; ++nb; }
    o += b * BM;
  }
  offs[NEXP] = o;
  nblk[0] = nb;
}

__global__ void k_fill(const int* __restrict__ top2i, const float* __restrict__ top2w,
                       const int* __restrict__ offs, int* __restrict__ fill,
                       int* __restrict__ perm, float* __restrict__ wrow) {
  const int id = blockIdx.x * blockDim.x + threadIdx.x;
  if (id >= T_TOK * 2) return;
  const int e = top2i[id];
  const int pos = atomicAdd(&fill[e], 1);
  const int r = offs[e] + pos;
  perm[r] = id >> 1;
  wrow[r] = top2w[id];
}

// ---------------- GEMM core (proven m97-structure inner loop) ----------------
// A bf16 [M][lda], Bt bf16 n-major [n][ldb]. Staging via global_load_lds 16B.
__device__ __forceinline__ void gemm_core(
    const u16* __restrict__ ap0, const u16* __restrict__ ap1,
    const u16* __restrict__ bp0, const u16* __restrict__ bp1, int K,
    u16* lA0, u16* lA1, u16* lB0, u16* lB1,
    const u16* aRd, const u16* bRd, f32x4 (&acc)[4][4]) {
  for (int k0 = 0; k0 < K; k0 += BK) {
    gld16(ap0 + k0, lA0);
    gld16(ap1 + k0, lA1);
    gld16(bp0 + k0, lB0);
    gld16(bp1 + k0, lB1);
    __syncthreads();
    bf16x8 af[4], bq[4];
#pragma unroll
    for (int i = 0; i < 4; ++i) af[i] = *(const bf16x8*)(aRd + i * 16 * BK);
#pragma unroll
    for (int j = 0; j < 4; ++j) bq[j] = *(const bf16x8*)(bRd + j * 16 * BK);
#pragma unroll
    for (int i = 0; i < 4; ++i)
#pragma unroll
      for (int j = 0; j < 4; ++j)
        acc[i][j] = __builtin_amdgcn_mfma_f32_16x16x32_bf16(af[i], bq[j], acc[i][j], 0, 0, 0);
    __syncthreads();
  }
}

// Fused up-projection: shared experts (bx<64) + routed experts (bx>=64).
// All blocks: K=2048, lda=ldb=2048, N-tile = by*128 (by<8 -> N=1024).
__global__ __launch_bounds__(256)
void k_up(const u16* __restrict__ xb, const u16* __restrict__ sw1t,
          const u16* __restrict__ w1t, u16* __restrict__ hbS,
          u16* __restrict__ hbR, const int* __restrict__ perm,
          const int* __restrict__ tbl_e, const int* __restrict__ tbl_r0,
          const int* __restrict__ nblk) {
  __shared__ u16 As[BM * BK];
  __shared__ u16 Bs[BN * BK];

  const int bx = blockIdx.x, by = blockIdx.y;
  const int tid = threadIdx.x;
  const int w = tid >> 6, lane = tid & 63;
  const int lr = lane >> 2;
  const int lk = (lane & 3) * 8;

  const bool routed = bx >= 64;
  int expert, r0, ra0, ra1;
  const u16* B;
  if (!routed) {
    expert = bx >> 5;                 // shared-expert index s
    r0 = (bx & 31) * BM;
    B = sw1t + (size_t)expert * (size_t)HIDD * DIMD;
    ra0 = r0 + w * 32 + lr; ra1 = ra0 + 16;
  } else {
    const int rbx = bx - 64;
    if (rbx >= *nblk) return;
    expert = tbl_e[rbx];
    r0 = tbl_r0[rbx];
    B = w1t + (size_t)expert * (size_t)HIDD * DIMD;
    const int rr0 = r0 + w * 32 + lr, rr1 = rr0 + 16;
    const int p0 = perm[rr0]; ra0 = (p0 < 0) ? 0 : p0;
    const int p1 = perm[rr1]; ra1 = (p1 < 0) ? 0 : p1;
  }

  const int n0 = by * BN;
  const u16* ap0 = xb + (size_t)ra0 * DIMD + lk;
  const u16* ap1 = xb + (size_t)ra1 * DIMD + lk;
  const u16* bp0 = B + (size_t)(n0 + w * 32 + lr) * DIMD + lk;
  const u16* bp1 = bp0 + (size_t)16 * DIMD;
  u16* lA0 = &As[w * 1024];
  u16* lA1 = &As[w * 1024 + 512];
  u16* lB0 = &Bs[w * 1024];
  u16* lB1 = &Bs[w * 1024 + 512];

  f32x4 acc[4][4];
#pragma unroll
  for (int i = 0; i < 4; ++i)
#pragma unroll
    for (int j = 0; j < 4; ++j) {
      acc[i][j][0] = 0.f; acc[i][j][1] = 0.f; acc[i][j][2] = 0.f; acc[i][j][3] = 0.f;
    }

  const int wr = (w >> 1) * 64, wc = (w & 1) * 64;
  const int lm = lane & 15, lq = lane >> 4;
  const u16* aRd = &As[(wr + lm) * BK + lq * 8];
  const u16* bRd = &Bs[(wc + lm) * BK + lq * 8];

  gemm_core(ap0, ap1, bp0, bp1, DIMD, lA0, lA1, lB0, lB1, aRd, bRd, acc);

#pragma unroll
  for (int i = 0; i < 4; ++i) {
#pragma unroll
    for (int r = 0; r < 4; ++r) {
      const int row = r0 + wr + i * 16 + lq * 4 + r;
      u16* dst = routed ? &hbR[(size_t)row * HIDD]
                        : &hbS[(size_t)row * DIMD + expert * HIDD];
#pragma unroll
      for (int j = 0; j < 4; ++j) {
        const int gc = n0 + wc + j * 16 + lm;
        const float v = acc[i][j][r];
        const float s = v / (1.f + expf(-v));
        dst[gc] = f2b(s);
      }
    }
  }
}

// Fused down-projection: shared (bx<32, K=2048 concat) + routed (bx>=32, K=1024).
// out is pre-zeroed; everything accumulates via atomicAdd. by<16 -> N=2048.
__global__ __launch_bounds__(256)
void k_down(const u16* __restrict__ hbS, const u16* __restrict__ hbR,
            const u16* __restrict__ sw2ct, const u16* __restrict__ w2t,
            float* __restrict__ out, const int* __restrict__ perm,
            const float* __restrict__ wrow,
            const int* __restrict__ tbl_e, const int* __restrict__ tbl_r0,
            const int* __restrict__ nblk) {
  __shared__ u16 As[BM * BK];
  __shared__ u16 Bs[BN * BK];

  const int bx = blockIdx.x, by = blockIdx.y;
  const int tid = threadIdx.x;
  const int w = tid >> 6, lane = tid & 63;
  const int lr = lane >> 2;
  const int lk = (lane & 3) * 8;

  const bool routed = bx >= 32;
  int r0, K, ld;
  const u16 *Amat, *B;
  if (!routed) {
    r0 = bx * BM;
    Amat = hbS; K = DIMD; ld = DIMD;
    B = sw2ct;
  } else {
    const int rbx = bx - 32;
    if (rbx >= *nblk) return;
    const int expert = tbl_e[rbx];
    r0 = tbl_r0[rbx];
    Amat = hbR; K = HIDD; ld = HIDD;
    B = w2t + (size_t)expert * (size_t)DIMD * HIDD;
  }

  const int n0 = by * BN;
  const u16* ap0 = Amat + (size_t)(r0 + w * 32 + lr) * ld + lk;
  const u16* ap1 = ap0 + (size_t)16 * ld;
  const u16* bp0 = B + (size_t)(n0 + w * 32 + lr) * ld + lk;
  const u16* bp1 = bp0 + (size_t)16 * ld;
  u16* lA0 = &As[w * 1024];
  u16* lA1 = &As[w * 1024 + 512];
  u16* lB0 = &Bs[w * 1024];
  u16* lB1 = &Bs[w * 1024 + 512];

  f32x4 acc[4][4];
#pragma unroll
  for (int i = 0; i < 4; ++i)
#pragma unroll
    for (int j = 0; j < 4; ++j) {
      acc[i][j][0] = 0.f; acc[i][j][1] = 0.f; acc[i][j][2] = 0.f; acc[i][j][3] = 0.f;
    }

  const int wr = (w >> 1) * 64, wc = (w & 1) * 64;
  const int lm = lane & 15, lq = lane >> 4;
  const u16* aRd = &As[(wr + lm) * BK + lq * 8];
  const u16* bRd = &Bs[(wc + lm) * BK + lq * 8];

  gemm_core(ap0, ap1, bp0, bp1, K, lA0, lA1, lB0, lB1, aRd, bRd, acc);

#pragma unroll
  for (int i = 0; i < 4; ++i) {
#pragma unroll
    for (int r = 0; r < 4; ++r) {
      const int rr = r0 + wr + i * 16 + lq * 4 + r;
      int t; float wt;
      if (!routed) { t = rr; wt = 1.f; }
      else { t = perm[rr]; wt = (t >= 0) ? wrow[rr] : 0.f; }
      if (t >= 0) {
        float* dst = &out[(size_t)t * DIMD];
#pragma unroll
        for (int j = 0; j < 4; ++j) {
          const int gc = n0 + wc + j * 16 + lm;
          atomicAdd(&dst[gc], wt * acc[i][j][r]);
        }
      }
    }
  }
}

// ---------------- launch ----------------

extern "C" void kernel_launch(void* const* d_in, const int* in_sizes, int n_in,
                              void* d_out, int out_size, void* d_ws, size_t ws_size,
                              hipStream_t stream) {
  const float* x   = (const float*)d_in[0];
  const float* gw  = (const float*)d_in[1];
  const float* sw1 = (const float*)d_in[2];
  const float* sw2 = (const float*)d_in[3];
  const float* w1  = (const float*)d_in[4];
  const float* w2  = (const float*)d_in[5];
  float* out = (float*)d_out;

  char* ws = (char*)d_ws;
  u16* xb    = (u16*)(ws);                         // 16 MB
  u16* hbS   = (u16*)(ws + (size_t)( 16 << 20));   // 16 MB
  u16* hbR   = (u16*)(ws + (size_t)( 32 << 20));   // 20 MB
  u16* sw1t  = (u16*)(ws + (size_t)( 52 << 20));   //  8 MB  [2][1024][2048]
  u16* sw2ct = (u16*)(ws + (size_t)( 60 << 20));   //  8 MB  [2048][2*1024] concat
  u16* w1t   = (u16*)(ws + (size_t)( 68 << 20));   // 64 MB  [16][1024][2048]
  u16* w2t   = (u16*)(ws + (size_t)(132 << 20));   // 64 MB  [16][2048][1024]
  char* p = ws + (size_t)(196 << 20);
  int*   top2i   = (int*)p;    p += T_TOK * 2 * 4;
  float* top2w   = (float*)p;  p += T_TOK * 2 * 4;
  int*   perm    = (int*)p;    p += RMAX * 4;
  float* wrow    = (float*)p;  p += RMAX * 4;
  int*   cnt     = (int*)p;    p += 16 * 4;
  int*   fill    = (int*)p;    p += 16 * 4;
  int*   offs    = (int*)p;    p += 32 * 4;
  int*   tbl_e   = (int*)p;    p += MAXBLK * 4;
  int*   tbl_r0  = (int*)p;    p += MAXBLK * 4;
  int*   nblk    = (int*)p;    p += 16 * 4;
  float* partial = (float*)p;  p += 256 * 16 * 4;

  // out must be zero before k_down's atomic accumulation
  k_zero<<<(T_TOK * DIMD / 4) / 256, 256, 0, stream>>>(out);
  k_init<<<(RMAX + 255) / 256, 256, 0, stream>>>(perm, cnt, fill);
  k_cvt<<<(T_TOK * DIMD / 4) / 256, 256, 0, stream>>>(x, xb);
  k_gate<<<T_TOK / 16, 256, 0, stream>>>(x, gw, top2i, top2w, cnt, partial);
  k_off<<<1, 64, 0, stream>>>(cnt, offs, tbl_e, tbl_r0, nblk);
  k_fill<<<(T_TOK * 2 + 255) / 256, 256, 0, stream>>>(top2i, top2w, offs, fill, perm, wrow);
  k_aux<<<1, 256, 0, stream>>>(partial, out + (size_t)T_TOK * DIMD);

  // weight transposes (fp32 [K][N] -> bf16 [n][k])
  k_tr<<<dim3(1024 / 64, 2048 / 64,  2), 256, 0, stream>>>(sw1, sw1t, 2048, 1024, 1024l * 2048, 2048);
  k_tr<<<dim3(2048 / 64, 1024 / 64,  2), 256, 0, stream>>>(sw2, sw2ct, 1024, 2048, 1024, 2048);
  k_tr<<<dim3(1024 / 64, 2048 / 64, 16), 256, 0, stream>>>(w1, w1t, 2048, 1024, 1024l * 2048, 2048);
  k_tr<<<dim3(2048 / 64, 1024 / 64, 16), 256, 0, stream>>>(w2, w2t, 1024, 2048, 2048l * 1024, 1024);

  // fused up-projection: 64 shared blocks + up to 80 routed blocks, 8 col-tiles
  k_up<<<dim3(64 + 80, 8), 256, 0, stream>>>(xb, sw1t, w1t, hbS, hbR,
                                             perm, tbl_e, tbl_r0, nblk);
  // fused down-projection: 32 shared blocks + up to 80 routed blocks, 16 col-tiles
  k_down<<<dim3(32 + 80, 16), 256, 0, stream>>>(hbS, hbR, sw2ct, w2t, out,
                                                perm, wrow, tbl_e, tbl_r0, nblk);
}